// Round 1
// baseline (606.186 us; speedup 1.0000x reference)
//
#include <hip/hip_runtime.h>

// ---------------------------------------------------------------------------
// CausalSelfAttention forward on MI355X (gfx950).
// B=4, T=2048, C=1024, H=16, hs=64.
// Pipeline: [cvt x->bf16, transpose W's] -> QKV GEMM (bf16 MFMA) ->
//           flash attention (bf16 MFMA, f32 online softmax) -> proj GEMM.
// Workspace layout (bytes):
//   xb    @ 0         : 8192x1024 bf16           (16,777,216)
//   WaT   @ 16777216  : 3072x1024 bf16           ( 6,291,456)
//   WpT   @ 23068672  : 1024x1024 bf16           ( 2,097,152)
//   Q     @ 25165824  : [64][2048][64] bf16      (16,777,216)  (pre-scaled by 1/8)
//   K     @ 41943040  : [64][2048][64] bf16      (16,777,216)
//   Vt    @ 58720256  : [64][64][2048] bf16      (16,777,216)  (V transposed per head)
//   Y     @ 75497472  : 8192x1024 bf16           (16,777,216)
// total ~92.3 MB
// ---------------------------------------------------------------------------

typedef __bf16 bf16_t;
typedef __bf16 bf16x8 __attribute__((ext_vector_type(8)));
typedef __bf16 bf16x4 __attribute__((ext_vector_type(4)));
typedef float  f32x4  __attribute__((ext_vector_type(4)));

#define MFMA16(a, b, c) __builtin_amdgcn_mfma_f32_16x16x32_bf16((a), (b), (c), 0, 0, 0)

static __device__ __forceinline__ void gld_lds16(const bf16_t* g, void* l) {
  // 16B-per-lane async global->LDS. LDS dest is wave-uniform base + lane*16.
  __builtin_amdgcn_global_load_lds(
      (const __attribute__((address_space(1))) void*)(const void*)g,
      (__attribute__((address_space(3))) void*)l, 16, 0, 0);
}

static __device__ __forceinline__ bf16x8 ldv8(const void* p) {
  return *reinterpret_cast<const bf16x8*>(p);
}

// ---------------------------------------------------------------- prep ----
__global__ __launch_bounds__(256) void cvt_f32_bf16(const float* __restrict__ in,
                                                    bf16_t* __restrict__ out, int n4) {
  int i = blockIdx.x * 256 + threadIdx.x;
  if (i < n4) {
    float4 v = reinterpret_cast<const float4*>(in)[i];
    bf16x4 o;
    o[0] = (bf16_t)v.x; o[1] = (bf16_t)v.y; o[2] = (bf16_t)v.z; o[3] = (bf16_t)v.w;
    reinterpret_cast<bf16x4*>(out)[i] = o;
  }
}

// in [Kd][Nd] f32  ->  out [Nd][Kd] bf16
__global__ __launch_bounds__(256) void transpose_cvt(const float* __restrict__ in,
                                                     bf16_t* __restrict__ out,
                                                     int Kd, int Nd) {
  __shared__ float tile[32][33];
  int tx = threadIdx.x, ty = threadIdx.y;
  int n0 = blockIdx.x * 32, k0 = blockIdx.y * 32;
#pragma unroll
  for (int i = 0; i < 4; ++i)
    tile[ty + i * 8][tx] = in[(size_t)(k0 + ty + i * 8) * Nd + (n0 + tx)];
  __syncthreads();
#pragma unroll
  for (int i = 0; i < 4; ++i)
    out[(size_t)(n0 + ty + i * 8) * Kd + (k0 + tx)] = (bf16_t)tile[tx][ty + i * 8];
}

// ---------------------------------------------------------------- GEMM ----
// C[M][N] = A[M][K] * Bt[N][K]^T + bias.  128x128 tile, BK=64, 4 waves (2x2),
// each wave 64x64 = 4x4 mfma_16x16x32 fragments. global_load_lds staging with
// XOR swizzle applied on the global-source side (linear LDS dest, G21).
// MODE 0: scatter qkv -> Q (x0.125), K, Vt (bf16).  MODE 1: f32 out.
template <int MODE>
__global__ __launch_bounds__(256) void gemm_bf16(
    const bf16_t* __restrict__ A, const bf16_t* __restrict__ Bt,
    const float* __restrict__ bias, int M, int N, int K,
    bf16_t* __restrict__ Qo, bf16_t* __restrict__ Ko, bf16_t* __restrict__ Vt,
    float* __restrict__ Co) {
  __shared__ alignas(16) char lds[32768];  // A tile 16KB @0, B tile 16KB @16384

  const int tid = threadIdx.x;
  const int wave = tid >> 6, lane = tid & 63;
  const int wm = wave >> 1, wn = wave & 1;
  const int l16 = lane & 15, kb = lane >> 4;
  const int tm0 = blockIdx.y * 128, tn0 = blockIdx.x * 128;
  const int srow = wave * 8 + (lane >> 3);  // staging row within 32-row inst block
  const int sp = lane & 7;                  // physical 16B slot within 128B row

  f32x4 acc[4][4] = {};

  for (int k0 = 0; k0 < K; k0 += 64) {
    __syncthreads();
#pragma unroll
    for (int inst = 0; inst < 4; ++inst) {
      const int row = inst * 32 + srow;
      const int chunk = (sp ^ (row & 7)) * 8;  // pre-swizzled global source
      gld_lds16(A + (size_t)(tm0 + row) * K + k0 + chunk,
                &lds[inst * 4096 + wave * 1024]);
      gld_lds16(Bt + (size_t)(tn0 + row) * K + k0 + chunk,
                &lds[16384 + inst * 4096 + wave * 1024]);
    }
    __syncthreads();  // drains vmcnt(0): tiles ready
#pragma unroll
    for (int kc = 0; kc < 2; ++kc) {
      bf16x8 af[4], bfr[4];
#pragma unroll
      for (int mi = 0; mi < 4; ++mi) {
        const int row = wm * 64 + mi * 16 + l16;
        const int slot = (kc * 4 + kb) ^ (row & 7);
        af[mi] = ldv8(&lds[row * 128 + slot * 16]);
      }
#pragma unroll
      for (int ni = 0; ni < 4; ++ni) {
        const int row = wn * 64 + ni * 16 + l16;
        const int slot = (kc * 4 + kb) ^ (row & 7);
        bfr[ni] = ldv8(&lds[16384 + row * 128 + slot * 16]);
      }
#pragma unroll
      for (int mi = 0; mi < 4; ++mi)
#pragma unroll
        for (int ni = 0; ni < 4; ++ni)
          acc[mi][ni] = MFMA16(af[mi], bfr[ni], acc[mi][ni]);
    }
  }

  // epilogue: C/D layout col=lane&15, row=(lane>>4)*4+j  [verified m89]
#pragma unroll
  for (int ni = 0; ni < 4; ++ni) {
    const int n = tn0 + wn * 64 + ni * 16 + l16;
    const float bv = bias[n];
#pragma unroll
    for (int mi = 0; mi < 4; ++mi) {
#pragma unroll
      for (int j = 0; j < 4; ++j) {
        const int m = tm0 + wm * 64 + mi * 16 + kb * 4 + j;
        const float v = acc[mi][ni][j] + bv;
        if constexpr (MODE == 0) {
          const int which = n >> 10, hn = n & 1023;
          const int h = hn >> 6, d = hn & 63;
          const int b = m >> 11, t = m & 2047;
          const size_t bh = (size_t)(b * 16 + h);
          if (which == 0)
            Qo[(bh * 2048 + t) * 64 + d] = (bf16_t)(v * 0.125f);  // fold 1/sqrt(hs), exact
          else if (which == 1)
            Ko[(bh * 2048 + t) * 64 + d] = (bf16_t)v;
          else
            Vt[(bh * 64 + d) * 2048 + t] = (bf16_t)v;  // V transposed per head
        } else {
          Co[(size_t)m * N + n] = v;
        }
      }
    }
  }
}

// ----------------------------------------------------------- attention ----
// 4 waves/block, 16 q-rows/wave, KVBLK=32. K/V fragments straight from global
// (K,V per head = 512KB, L2-resident). Online softmax in f32; P re-laid-out
// via tiny per-wave LDS tile for the PV A-operand.
__global__ __launch_bounds__(256) void attn_fwd(const bf16_t* __restrict__ Qg,
                                                const bf16_t* __restrict__ Kg,
                                                const bf16_t* __restrict__ Vtg,
                                                bf16_t* __restrict__ Yg) {
  __shared__ alignas(16) bf16_t Pl[4][16][48];  // stride 96B: 16B-aligned rows
  const int tid = threadIdx.x;
  const int wave = tid >> 6, lane = tid & 63;
  const int l16 = lane & 15, kb = lane >> 4;
  const int bh = blockIdx.y;
  const size_t base = (size_t)bh * (2048 * 64);
  const int q0 = blockIdx.x * 64 + wave * 16;

  const bf16x8 qf0 = ldv8(Qg + base + (size_t)(q0 + l16) * 64 + kb * 8);
  const bf16x8 qf1 = ldv8(Qg + base + (size_t)(q0 + l16) * 64 + 32 + kb * 8);

  f32x4 o0 = {0.f, 0.f, 0.f, 0.f}, o1 = o0, o2 = o0, o3 = o0;
  float mr[4] = {-1e30f, -1e30f, -1e30f, -1e30f};
  float lr[4] = {0.f, 0.f, 0.f, 0.f};

  // uniform trip count across the block's 4 waves so __syncthreads is legal
  const int ntiles = blockIdx.x * 2 + 2;
  for (int t = 0; t < ntiles; ++t) {
    const int kv0 = t * 32;
    const bf16_t* Kb = Kg + base + (size_t)kv0 * 64;
    f32x4 s0 = {0.f, 0.f, 0.f, 0.f}, s1 = s0;
    s0 = MFMA16(qf0, ldv8(Kb + (size_t)l16 * 64 + kb * 8), s0);
    s0 = MFMA16(qf1, ldv8(Kb + (size_t)l16 * 64 + 32 + kb * 8), s0);
    s1 = MFMA16(qf0, ldv8(Kb + (size_t)(16 + l16) * 64 + kb * 8), s1);
    s1 = MFMA16(qf1, ldv8(Kb + (size_t)(16 + l16) * 64 + 32 + kb * 8), s1);

    const int kvc0 = kv0 + l16, kvc1 = kvc0 + 16;
    float e0[4], e1[4];
#pragma unroll
    for (int j = 0; j < 4; ++j) {
      const int qr = q0 + kb * 4 + j;
      const float v0 = (kvc0 <= qr) ? s0[j] : -1e30f;
      const float v1 = (kvc1 <= qr) ? s1[j] : -1e30f;
      float mx = fmaxf(v0, v1);
      mx = fmaxf(mx, __shfl_xor(mx, 1));
      mx = fmaxf(mx, __shfl_xor(mx, 2));
      mx = fmaxf(mx, __shfl_xor(mx, 4));
      mx = fmaxf(mx, __shfl_xor(mx, 8));
      const float mn = fmaxf(mr[j], mx);
      const float sc = __expf(mr[j] - mn);
      const float p0 = __expf(v0 - mn);
      const float p1 = __expf(v1 - mn);
      float ss = p0 + p1;
      ss += __shfl_xor(ss, 1);
      ss += __shfl_xor(ss, 2);
      ss += __shfl_xor(ss, 4);
      ss += __shfl_xor(ss, 8);
      lr[j] = lr[j] * sc + ss;
      mr[j] = mn;
      o0[j] *= sc; o1[j] *= sc; o2[j] *= sc; o3[j] *= sc;
      e0[j] = p0; e1[j] = p1;
    }
#pragma unroll
    for (int j = 0; j < 4; ++j) {
      Pl[wave][kb * 4 + j][l16] = (bf16_t)e0[j];
      Pl[wave][kb * 4 + j][16 + l16] = (bf16_t)e1[j];
    }
    __syncthreads();  // lgkmcnt drain: intra-wave P write->read ordering
    const bf16x8 pa = ldv8(&Pl[wave][l16][kb * 8]);
    const bf16_t* Vb = Vtg + (size_t)bh * (64 * 2048) + kv0;
    o0 = MFMA16(pa, ldv8(Vb + (size_t)l16 * 2048 + kb * 8), o0);
    o1 = MFMA16(pa, ldv8(Vb + (size_t)(16 + l16) * 2048 + kb * 8), o1);
    o2 = MFMA16(pa, ldv8(Vb + (size_t)(32 + l16) * 2048 + kb * 8), o2);
    o3 = MFMA16(pa, ldv8(Vb + (size_t)(48 + l16) * 2048 + kb * 8), o3);
  }

  const int b = bh >> 4, h = bh & 15;
#pragma unroll
  for (int j = 0; j < 4; ++j) {
    const float inv = 1.0f / lr[j];
    const int trow = q0 + kb * 4 + j;
    bf16_t* yp = Yg + ((size_t)(b * 2048 + trow)) * 1024 + h * 64 + l16;
    yp[0] = (bf16_t)(o0[j] * inv);
    yp[16] = (bf16_t)(o1[j] * inv);
    yp[32] = (bf16_t)(o2[j] * inv);
    yp[48] = (bf16_t)(o3[j] * inv);
  }
}

// --------------------------------------------------------------- launch ---
extern "C" void kernel_launch(void* const* d_in, const int* in_sizes, int n_in,
                              void* d_out, int out_size, void* d_ws, size_t ws_size,
                              hipStream_t stream) {
  const float* x = (const float*)d_in[0];
  const float* W_attn = (const float*)d_in[1];
  const float* b_attn = (const float*)d_in[2];
  const float* W_proj = (const float*)d_in[3];
  const float* b_proj = (const float*)d_in[4];
  float* out = (float*)d_out;

  char* ws = (char*)d_ws;
  bf16_t* xb  = (bf16_t*)(ws + 0);
  bf16_t* WaT = (bf16_t*)(ws + 16777216);
  bf16_t* WpT = (bf16_t*)(ws + 23068672);
  bf16_t* Qb  = (bf16_t*)(ws + 25165824);
  bf16_t* Kb  = (bf16_t*)(ws + 41943040);
  bf16_t* Vt  = (bf16_t*)(ws + 58720256);
  bf16_t* Yb  = (bf16_t*)(ws + 75497472);

  // prep
  cvt_f32_bf16<<<8192, 256, 0, stream>>>(x, xb, 8192 * 1024 / 4);
  transpose_cvt<<<dim3(96, 32), dim3(32, 8), 0, stream>>>(W_attn, WaT, 1024, 3072);
  transpose_cvt<<<dim3(32, 32), dim3(32, 8), 0, stream>>>(W_proj, WpT, 1024, 1024);

  // qkv = x @ W_attn + b_attn, scattered to Q(x1/8)/K/Vt
  gemm_bf16<0><<<dim3(24, 64), 256, 0, stream>>>(xb, WaT, b_attn, 8192, 3072, 1024,
                                                 Qb, Kb, Vt, nullptr);
  // flash attention
  attn_fwd<<<dim3(32, 64), 256, 0, stream>>>(Qb, Kb, Vt, Yb);

  // out = y @ W_proj + b_proj
  gemm_bf16<1><<<dim3(8, 64), 256, 0, stream>>>(Yb, WpT, b_proj, 8192, 1024, 1024,
                                                nullptr, nullptr, nullptr, out);
}

// Round 2
// 355.514 us; speedup vs baseline: 1.7051x; 1.7051x over previous
//
#include <hip/hip_runtime.h>

// ---------------------------------------------------------------------------
// CausalSelfAttention forward on MI355X (gfx950).
// B=4, T=2048, C=1024, H=16, hs=64.
// Pipeline: [cvt x->bf16, transpose W's] -> QKV GEMM (bf16 MFMA) ->
//           flash attention (swapped-QK, waveindependent) -> proj GEMM.
// Workspace layout (bytes):
//   xb    @ 0         : 8192x1024 bf16           (16,777,216)
//   WaT   @ 16777216  : 3072x1024 bf16           ( 6,291,456)
//   WpT   @ 23068672  : 1024x1024 bf16           ( 2,097,152)
//   Q     @ 25165824  : [64][2048][64] bf16      (16,777,216)  (pre-scaled by 1/8)
//   K     @ 41943040  : [64][2048][64] bf16      (16,777,216)
//   Vt    @ 58720256  : [64][64][2048] bf16      (16,777,216)  (V transposed per head)
//   Y     @ 75497472  : 8192x1024 bf16           (16,777,216)
// ---------------------------------------------------------------------------

typedef __bf16 bf16_t;
typedef __bf16 bf16x8 __attribute__((ext_vector_type(8)));
typedef __bf16 bf16x4 __attribute__((ext_vector_type(4)));
typedef float  f32x4  __attribute__((ext_vector_type(4)));

#define MFMA16(a, b, c) __builtin_amdgcn_mfma_f32_16x16x32_bf16((a), (b), (c), 0, 0, 0)

static __device__ __forceinline__ void gld_lds16(const bf16_t* g, void* l) {
  __builtin_amdgcn_global_load_lds(
      (const __attribute__((address_space(1))) void*)(const void*)g,
      (__attribute__((address_space(3))) void*)l, 16, 0, 0);
}

static __device__ __forceinline__ bf16x8 ldv8(const void* p) {
  return *reinterpret_cast<const bf16x8*>(p);
}

// ---------------------------------------------------------------- prep ----
__global__ __launch_bounds__(256) void cvt_f32_bf16(const float* __restrict__ in,
                                                    bf16_t* __restrict__ out, int n4) {
  int i = blockIdx.x * 256 + threadIdx.x;
  if (i < n4) {
    float4 v = reinterpret_cast<const float4*>(in)[i];
    bf16x4 o;
    o[0] = (bf16_t)v.x; o[1] = (bf16_t)v.y; o[2] = (bf16_t)v.z; o[3] = (bf16_t)v.w;
    reinterpret_cast<bf16x4*>(out)[i] = o;
  }
}

// in [Kd][Nd] f32  ->  out [Nd][Kd] bf16
__global__ __launch_bounds__(256) void transpose_cvt(const float* __restrict__ in,
                                                     bf16_t* __restrict__ out,
                                                     int Kd, int Nd) {
  __shared__ float tile[32][33];
  int tx = threadIdx.x, ty = threadIdx.y;
  int n0 = blockIdx.x * 32, k0 = blockIdx.y * 32;
#pragma unroll
  for (int i = 0; i < 4; ++i)
    tile[ty + i * 8][tx] = in[(size_t)(k0 + ty + i * 8) * Nd + (n0 + tx)];
  __syncthreads();
#pragma unroll
  for (int i = 0; i < 4; ++i)
    out[(size_t)(n0 + ty + i * 8) * Kd + (k0 + tx)] = (bf16_t)tile[tx][ty + i * 8];
}

// ---------------------------------------------------------------- GEMM ----
// (unchanged from round 1 — verified correct)
template <int MODE>
__global__ __launch_bounds__(256) void gemm_bf16(
    const bf16_t* __restrict__ A, const bf16_t* __restrict__ Bt,
    const float* __restrict__ bias, int M, int N, int K,
    bf16_t* __restrict__ Qo, bf16_t* __restrict__ Ko, bf16_t* __restrict__ Vt,
    float* __restrict__ Co) {
  __shared__ alignas(16) char lds[32768];

  const int tid = threadIdx.x;
  const int wave = tid >> 6, lane = tid & 63;
  const int wm = wave >> 1, wn = wave & 1;
  const int l16 = lane & 15, kb = lane >> 4;
  const int tm0 = blockIdx.y * 128, tn0 = blockIdx.x * 128;
  const int srow = wave * 8 + (lane >> 3);
  const int sp = lane & 7;

  f32x4 acc[4][4] = {};

  for (int k0 = 0; k0 < K; k0 += 64) {
    __syncthreads();
#pragma unroll
    for (int inst = 0; inst < 4; ++inst) {
      const int row = inst * 32 + srow;
      const int chunk = (sp ^ (row & 7)) * 8;
      gld_lds16(A + (size_t)(tm0 + row) * K + k0 + chunk,
                &lds[inst * 4096 + wave * 1024]);
      gld_lds16(Bt + (size_t)(tn0 + row) * K + k0 + chunk,
                &lds[16384 + inst * 4096 + wave * 1024]);
    }
    __syncthreads();
#pragma unroll
    for (int kc = 0; kc < 2; ++kc) {
      bf16x8 af[4], bfr[4];
#pragma unroll
      for (int mi = 0; mi < 4; ++mi) {
        const int row = wm * 64 + mi * 16 + l16;
        const int slot = (kc * 4 + kb) ^ (row & 7);
        af[mi] = ldv8(&lds[row * 128 + slot * 16]);
      }
#pragma unroll
      for (int ni = 0; ni < 4; ++ni) {
        const int row = wn * 64 + ni * 16 + l16;
        const int slot = (kc * 4 + kb) ^ (row & 7);
        bfr[ni] = ldv8(&lds[16384 + row * 128 + slot * 16]);
      }
#pragma unroll
      for (int mi = 0; mi < 4; ++mi)
#pragma unroll
        for (int ni = 0; ni < 4; ++ni)
          acc[mi][ni] = MFMA16(af[mi], bfr[ni], acc[mi][ni]);
    }
  }

#pragma unroll
  for (int ni = 0; ni < 4; ++ni) {
    const int n = tn0 + wn * 64 + ni * 16 + l16;
    const float bv = bias[n];
#pragma unroll
    for (int mi = 0; mi < 4; ++mi) {
#pragma unroll
      for (int j = 0; j < 4; ++j) {
        const int m = tm0 + wm * 64 + mi * 16 + kb * 4 + j;
        const float v = acc[mi][ni][j] + bv;
        if constexpr (MODE == 0) {
          const int which = n >> 10, hn = n & 1023;
          const int h = hn >> 6, d = hn & 63;
          const int b = m >> 11, t = m & 2047;
          const size_t bh = (size_t)(b * 16 + h);
          if (which == 0)
            Qo[(bh * 2048 + t) * 64 + d] = (bf16_t)(v * 0.125f);
          else if (which == 1)
            Ko[(bh * 2048 + t) * 64 + d] = (bf16_t)v;
          else
            Vt[(bh * 64 + d) * 2048 + t] = (bf16_t)v;
        } else {
          Co[(size_t)m * N + n] = v;
        }
      }
    }
  }
}

// ----------------------------------------------------------- attention ----
// Swapped-QK structure: per wave 16 q-rows, KVBLK=64, each lane owns ONE
// q-row (col of the swapped MFMA output). Softmax row-reduce = 15 in-reg ops
// + 2 shuffles. P^T re-laid-out via wave-private LDS (no barriers anywhere).
// K prefetched 1 tile ahead into regs; V issued at body top.
// Block handles q-tile pair (pp, 31-pp) -> uniform 33 kv-tiles/block.
// bh grouped 8-per-XCD via linear-id swizzle for K/V L2 residence.
__global__ __launch_bounds__(256) void attn_fwd(const bf16_t* __restrict__ Qg,
                                                const bf16_t* __restrict__ Kg,
                                                const bf16_t* __restrict__ Vtg,
                                                bf16_t* __restrict__ Yg) {
  __shared__ alignas(16) bf16_t Pl[4][16][80];  // row stride 160B (16B-aligned, depowered stride)
  const int tid = threadIdx.x;
  const int wave = tid >> 6, lane = tid & 63;
  const int l16 = lane & 15, kb = lane >> 4;

  const int n = blockIdx.x;                    // 1024 blocks
  const int bh = (n & 7) * 8 + ((n >> 3) & 7); // 8 heads per XCD (id%8 heuristic)
  const int pp = n >> 6;                       // pair index [0,16)
  const size_t base = (size_t)bh * (2048 * 64);
  const bf16_t* Vtb = Vtg + (size_t)bh * (64 * 2048) + (size_t)l16 * 2048;
  bf16_t* Pw = &Pl[wave][0][0];

  const int b = bh >> 4, h = bh & 15;

  for (int pass = 0; pass < 2; ++pass) {
    const int qt = pass ? (31 - pp) : pp;      // q-tile index [0,32)
    const int q0 = qt * 64 + wave * 16;
    const int q = q0 + l16;                    // this lane's q-row
    const int trips = qt + 1;

    const bf16x8 qf0 = ldv8(Qg + base + (size_t)q * 64 + kb * 8);
    const bf16x8 qf1 = ldv8(Qg + base + (size_t)q * 64 + 32 + kb * 8);

    f32x4 o[4] = {};
    float m_r = -1e30f, l_r = 0.f;

    bf16x8 ck[8];
    {
      const bf16_t* Kb = Kg + base;
#pragma unroll
      for (int i = 0; i < 4; ++i) {
        ck[i * 2 + 0] = ldv8(Kb + (size_t)(i * 16 + l16) * 64 + kb * 8);
        ck[i * 2 + 1] = ldv8(Kb + (size_t)(i * 16 + l16) * 64 + 32 + kb * 8);
      }
    }

    for (int t = 0; t < trips; ++t) {
      const int kv0 = t * 64;
      // V fragments for this tile (issued early; consumed after softmax)
      bf16x8 vf[8];
#pragma unroll
      for (int i = 0; i < 4; ++i) {
        vf[i * 2 + 0] = ldv8(Vtb + (size_t)(i * 16) * 2048 + kv0 + kb * 8);
        vf[i * 2 + 1] = ldv8(Vtb + (size_t)(i * 16) * 2048 + kv0 + 32 + kb * 8);
      }
      // prefetch next K tile
      bf16x8 nk[8];
      const bool more = (t + 1 < trips);
      if (more) {
        const bf16_t* Kb = Kg + base + (size_t)(kv0 + 64) * 64;
#pragma unroll
        for (int i = 0; i < 4; ++i) {
          nk[i * 2 + 0] = ldv8(Kb + (size_t)(i * 16 + l16) * 64 + kb * 8);
          nk[i * 2 + 1] = ldv8(Kb + (size_t)(i * 16 + l16) * 64 + 32 + kb * 8);
        }
      }
      // swapped QK^T: s[i] holds S^T[kv = kv0+i*16+kb*4+j][q = q0+l16]
      f32x4 s[4] = {};
#pragma unroll
      for (int i = 0; i < 4; ++i) {
        s[i] = MFMA16(ck[i * 2 + 0], qf0, s[i]);
        s[i] = MFMA16(ck[i * 2 + 1], qf1, s[i]);
      }
      // causal mask + lane-local max over 16 regs
      float mx = -1e30f;
#pragma unroll
      for (int i = 0; i < 4; ++i)
#pragma unroll
        for (int j = 0; j < 4; ++j) {
          const int kv = kv0 + i * 16 + kb * 4 + j;
          const float v = (kv <= q) ? s[i][j] : -1e30f;
          s[i][j] = v;
          mx = fmaxf(mx, v);
        }
      mx = fmaxf(mx, __shfl_xor(mx, 16));
      mx = fmaxf(mx, __shfl_xor(mx, 32));
      const float mn = fmaxf(m_r, mx);
      const float sc = __expf(m_r - mn);
      float ss = 0.f;
      bf16x4 pw[4];
#pragma unroll
      for (int i = 0; i < 4; ++i)
#pragma unroll
        for (int j = 0; j < 4; ++j) {
          const float p = __expf(s[i][j] - mn);
          ss += p;
          pw[i][j] = (bf16_t)p;
        }
      ss += __shfl_xor(ss, 16);
      ss += __shfl_xor(ss, 32);
      l_r = l_r * sc + ss;
      m_r = mn;
#pragma unroll
      for (int i = 0; i < 4; ++i) {
        o[i][0] *= sc; o[i][1] *= sc; o[i][2] *= sc; o[i][3] *= sc;
      }
      // P^T round-trip through wave-private LDS (no barrier: same-wave lgkmcnt)
#pragma unroll
      for (int i = 0; i < 4; ++i)
        *reinterpret_cast<bf16x4*>(&Pw[l16 * 80 + i * 16 + kb * 4]) = pw[i];
      const bf16x8 pb0 = ldv8(&Pw[l16 * 80 + kb * 8]);
      const bf16x8 pb1 = ldv8(&Pw[l16 * 80 + 32 + kb * 8]);
      // PV: o[i] = O^T[d = i*16+kb*4+j][q]
#pragma unroll
      for (int i = 0; i < 4; ++i) {
        o[i] = MFMA16(vf[i * 2 + 0], pb0, o[i]);
        o[i] = MFMA16(vf[i * 2 + 1], pb1, o[i]);
      }
      if (more) {
#pragma unroll
        for (int r = 0; r < 8; ++r) ck[r] = nk[r];
      }
    }

    const float inv = 1.0f / l_r;
    bf16_t* yrow = Yg + ((size_t)(b * 2048 + q)) * 1024 + h * 64;
#pragma unroll
    for (int i = 0; i < 4; ++i) {
      bf16x4 yv;
      yv[0] = (bf16_t)(o[i][0] * inv);
      yv[1] = (bf16_t)(o[i][1] * inv);
      yv[2] = (bf16_t)(o[i][2] * inv);
      yv[3] = (bf16_t)(o[i][3] * inv);
      *reinterpret_cast<bf16x4*>(yrow + i * 16 + kb * 4) = yv;
    }
  }
}

// --------------------------------------------------------------- launch ---
extern "C" void kernel_launch(void* const* d_in, const int* in_sizes, int n_in,
                              void* d_out, int out_size, void* d_ws, size_t ws_size,
                              hipStream_t stream) {
  const float* x = (const float*)d_in[0];
  const float* W_attn = (const float*)d_in[1];
  const float* b_attn = (const float*)d_in[2];
  const float* W_proj = (const float*)d_in[3];
  const float* b_proj = (const float*)d_in[4];
  float* out = (float*)d_out;

  char* ws = (char*)d_ws;
  bf16_t* xb  = (bf16_t*)(ws + 0);
  bf16_t* WaT = (bf16_t*)(ws + 16777216);
  bf16_t* WpT = (bf16_t*)(ws + 23068672);
  bf16_t* Qb  = (bf16_t*)(ws + 25165824);
  bf16_t* Kb  = (bf16_t*)(ws + 41943040);
  bf16_t* Vt  = (bf16_t*)(ws + 58720256);
  bf16_t* Yb  = (bf16_t*)(ws + 75497472);

  cvt_f32_bf16<<<8192, 256, 0, stream>>>(x, xb, 8192 * 1024 / 4);
  transpose_cvt<<<dim3(96, 32), dim3(32, 8), 0, stream>>>(W_attn, WaT, 1024, 3072);
  transpose_cvt<<<dim3(32, 32), dim3(32, 8), 0, stream>>>(W_proj, WpT, 1024, 1024);

  gemm_bf16<0><<<dim3(24, 64), 256, 0, stream>>>(xb, WaT, b_attn, 8192, 3072, 1024,
                                                 Qb, Kb, Vt, nullptr);

  attn_fwd<<<1024, 256, 0, stream>>>(Qb, Kb, Vt, Yb);

  gemm_bf16<1><<<dim3(8, 64), 256, 0, stream>>>(Yb, WpT, b_proj, 8192, 1024, 1024,
                                                nullptr, nullptr, nullptr, out);
}

// Round 3
// 211.012 us; speedup vs baseline: 2.8728x; 1.6848x over previous
//
#include <hip/hip_runtime.h>

// ---------------------------------------------------------------------------
// CausalSelfAttention forward on MI355X (gfx950).
// B=4, T=2048, C=1024, H=16, hs=64.
// Pipeline: [cvt x->bf16, transpose W's] -> QKV GEMM (bf16 MFMA) ->
//           flash attention (swapped-QK, LDS-staged K/V, 2-phase pipeline) ->
//           proj GEMM.
// Workspace layout (bytes):
//   xb    @ 0         : 8192x1024 bf16           (16,777,216)
//   WaT   @ 16777216  : 3072x1024 bf16           ( 6,291,456)
//   WpT   @ 23068672  : 1024x1024 bf16           ( 2,097,152)
//   Q     @ 25165824  : [64][2048][64] bf16      (16,777,216)  (pre-scaled by 1/8)
//   K     @ 41943040  : [64][2048][64] bf16      (16,777,216)
//   Vt    @ 58720256  : [64][64][2048] bf16      (16,777,216)  (V transposed per head)
//   Y     @ 75497472  : 8192x1024 bf16           (16,777,216)
// ---------------------------------------------------------------------------

typedef __bf16 bf16_t;
typedef __bf16 bf16x8 __attribute__((ext_vector_type(8)));
typedef __bf16 bf16x4 __attribute__((ext_vector_type(4)));
typedef float  f32x4  __attribute__((ext_vector_type(4)));

#define MFMA16(a, b, c) __builtin_amdgcn_mfma_f32_16x16x32_bf16((a), (b), (c), 0, 0, 0)

static __device__ __forceinline__ void gld_lds16(const bf16_t* g, void* l) {
  __builtin_amdgcn_global_load_lds(
      (const __attribute__((address_space(1))) void*)(const void*)g,
      (__attribute__((address_space(3))) void*)l, 16, 0, 0);
}

static __device__ __forceinline__ bf16x8 ldv8(const void* p) {
  return *reinterpret_cast<const bf16x8*>(p);
}

// ---------------------------------------------------------------- prep ----
__global__ __launch_bounds__(256) void cvt_f32_bf16(const float* __restrict__ in,
                                                    bf16_t* __restrict__ out, int n4) {
  int i = blockIdx.x * 256 + threadIdx.x;
  if (i < n4) {
    float4 v = reinterpret_cast<const float4*>(in)[i];
    bf16x4 o;
    o[0] = (bf16_t)v.x; o[1] = (bf16_t)v.y; o[2] = (bf16_t)v.z; o[3] = (bf16_t)v.w;
    reinterpret_cast<bf16x4*>(out)[i] = o;
  }
}

// in [Kd][Nd] f32  ->  out [Nd][Kd] bf16
__global__ __launch_bounds__(256) void transpose_cvt(const float* __restrict__ in,
                                                     bf16_t* __restrict__ out,
                                                     int Kd, int Nd) {
  __shared__ float tile[32][33];
  int tx = threadIdx.x, ty = threadIdx.y;
  int n0 = blockIdx.x * 32, k0 = blockIdx.y * 32;
#pragma unroll
  for (int i = 0; i < 4; ++i)
    tile[ty + i * 8][tx] = in[(size_t)(k0 + ty + i * 8) * Nd + (n0 + tx)];
  __syncthreads();
#pragma unroll
  for (int i = 0; i < 4; ++i)
    out[(size_t)(n0 + ty + i * 8) * Kd + (k0 + tx)] = (bf16_t)tile[tx][ty + i * 8];
}

// ---------------------------------------------------------------- GEMM ----
// (unchanged — verified correct)
template <int MODE>
__global__ __launch_bounds__(256) void gemm_bf16(
    const bf16_t* __restrict__ A, const bf16_t* __restrict__ Bt,
    const float* __restrict__ bias, int M, int N, int K,
    bf16_t* __restrict__ Qo, bf16_t* __restrict__ Ko, bf16_t* __restrict__ Vt,
    float* __restrict__ Co) {
  __shared__ alignas(16) char lds[32768];

  const int tid = threadIdx.x;
  const int wave = tid >> 6, lane = tid & 63;
  const int wm = wave >> 1, wn = wave & 1;
  const int l16 = lane & 15, kb = lane >> 4;
  const int tm0 = blockIdx.y * 128, tn0 = blockIdx.x * 128;
  const int srow = wave * 8 + (lane >> 3);
  const int sp = lane & 7;

  f32x4 acc[4][4] = {};

  for (int k0 = 0; k0 < K; k0 += 64) {
    __syncthreads();
#pragma unroll
    for (int inst = 0; inst < 4; ++inst) {
      const int row = inst * 32 + srow;
      const int chunk = (sp ^ (row & 7)) * 8;
      gld_lds16(A + (size_t)(tm0 + row) * K + k0 + chunk,
                &lds[inst * 4096 + wave * 1024]);
      gld_lds16(Bt + (size_t)(tn0 + row) * K + k0 + chunk,
                &lds[16384 + inst * 4096 + wave * 1024]);
    }
    __syncthreads();
#pragma unroll
    for (int kc = 0; kc < 2; ++kc) {
      bf16x8 af[4], bfr[4];
#pragma unroll
      for (int mi = 0; mi < 4; ++mi) {
        const int row = wm * 64 + mi * 16 + l16;
        const int slot = (kc * 4 + kb) ^ (row & 7);
        af[mi] = ldv8(&lds[row * 128 + slot * 16]);
      }
#pragma unroll
      for (int ni = 0; ni < 4; ++ni) {
        const int row = wn * 64 + ni * 16 + l16;
        const int slot = (kc * 4 + kb) ^ (row & 7);
        bfr[ni] = ldv8(&lds[16384 + row * 128 + slot * 16]);
      }
#pragma unroll
      for (int mi = 0; mi < 4; ++mi)
#pragma unroll
        for (int ni = 0; ni < 4; ++ni)
          acc[mi][ni] = MFMA16(af[mi], bfr[ni], acc[mi][ni]);
    }
  }

#pragma unroll
  for (int ni = 0; ni < 4; ++ni) {
    const int n = tn0 + wn * 64 + ni * 16 + l16;
    const float bv = bias[n];
#pragma unroll
    for (int mi = 0; mi < 4; ++mi) {
#pragma unroll
      for (int j = 0; j < 4; ++j) {
        const int m = tm0 + wm * 64 + mi * 16 + kb * 4 + j;
        const float v = acc[mi][ni][j] + bv;
        if constexpr (MODE == 0) {
          const int which = n >> 10, hn = n & 1023;
          const int h = hn >> 6, d = hn & 63;
          const int b = m >> 11, t = m & 2047;
          const size_t bh = (size_t)(b * 16 + h);
          if (which == 0)
            Qo[(bh * 2048 + t) * 64 + d] = (bf16_t)(v * 0.125f);
          else if (which == 1)
            Ko[(bh * 2048 + t) * 64 + d] = (bf16_t)v;
          else
            Vt[(bh * 64 + d) * 2048 + t] = (bf16_t)v;
        } else {
          Co[(size_t)m * N + n] = v;
        }
      }
    }
  }
}

// ----------------------------------------------------------- attention ----
// 4 waves/block, 64 q-rows/block (16/wave, swapped-QK so each lane owns one
// q-row). K and V^T tiles (64x64 bf16 = 8KB each) staged cooperatively into
// double-buffered LDS via global_load_lds with pre-swizzled global source
// (XOR 16B-chunk swizzle -> conflict-free ds_read_b128). One counted
// vmcnt(0)+s_barrier per kv-tile: stage(t+1) issued before consume(t), so
// loads fly under compute. P^T round-trips through a swizzled wave-private
// LDS tile. Block handles q-tile pair (pp, 31-pp): uniform 33 tiles/block.
// bh grouped 8-per-XCD: per-XCD K/V working set = 4MB (L2-fit).
__global__ __launch_bounds__(256) void attn_fwd(const bf16_t* __restrict__ Qg,
                                                const bf16_t* __restrict__ Kg,
                                                const bf16_t* __restrict__ Vtg,
                                                bf16_t* __restrict__ Yg) {
  // K dbuf [2][8KB] @0, V dbuf [2][8KB] @16384, P [4 waves][2KB] @32768
  __shared__ alignas(16) char lds[40960];

  const int tid = threadIdx.x;
  const int wave = tid >> 6, lane = tid & 63;
  const int l16 = lane & 15, kb = lane >> 4;
  const int l8 = l16 & 7;

  const int n = blockIdx.x;                    // 1024 blocks
  const int bh = (n & 7) * 8 + ((n >> 3) & 7); // 8 heads per XCD
  const int pp = n >> 6;                       // pair index [0,16)
  const size_t base = (size_t)bh * (2048 * 64);
  const int b = bh >> 4, h = bh & 15;

  // staging thread mapping: row = inst*32 + (tid>>3), 16B chunk = tid&7,
  // global source chunk pre-swizzled so linear LDS == swizzled layout (G21)
  const int srow = tid >> 3;
  const int schunk = (tid & 7) ^ (srow & 7);
  const bf16_t* Ksrc = Kg + base + (size_t)srow * 64 + schunk * 8;
  const bf16_t* Vsrc = Vtg + base + (size_t)srow * 2048 + schunk * 8;

  char* Pw = lds + 32768 + wave * 2048;

  auto stage = [&](int buf, int kv0) {
    char* kd = lds + buf * 8192 + wave * 1024;
    char* vd = lds + 16384 + buf * 8192 + wave * 1024;
    const bf16_t* ks = Ksrc + (size_t)kv0 * 64;
    const bf16_t* vs = Vsrc + kv0;
#pragma unroll
    for (int inst = 0; inst < 2; ++inst) {
      gld_lds16(ks + (size_t)inst * 2048, kd + inst * 4096);
      gld_lds16(vs + (size_t)inst * 65536, vd + inst * 4096);
    }
  };

  for (int pass = 0; pass < 2; ++pass) {
    const int qt = pass ? (31 - pp) : pp;      // q-tile index [0,32)
    const int q0 = qt * 64 + wave * 16;
    const int q = q0 + l16;                    // this lane's q-row
    const int trips = qt + 1;

    const bf16x8 qf0 = ldv8(Qg + base + (size_t)q * 64 + kb * 8);
    const bf16x8 qf1 = ldv8(Qg + base + (size_t)q * 64 + 32 + kb * 8);

    f32x4 o[4] = {};
    float m_r = -1e30f, l_r = 0.f;

    // prologue: stage tile 0 into buf 0, drain, align
    stage(0, 0);
    asm volatile("s_waitcnt vmcnt(0)" ::: "memory");
    __builtin_amdgcn_s_barrier();
    __builtin_amdgcn_sched_barrier(0);

    int cur = 0;
    for (int t = 0; t < trips; ++t) {
      const int kv0 = t * 64;
      if (t + 1 < trips) stage(cur ^ 1, kv0 + 64);  // loads in flight under compute

      const char* Kb = lds + cur * 8192;
      const char* Vb = lds + 16384 + cur * 8192;

      // K fragments (swizzled ds_read_b128, conflict-free)
      bf16x8 kf[8];
#pragma unroll
      for (int i = 0; i < 4; ++i) {
        const int row = i * 16 + l16;
#pragma unroll
        for (int kc = 0; kc < 2; ++kc)
          kf[i * 2 + kc] = ldv8(Kb + row * 128 + (((kc * 4 + kb) ^ (row & 7)) * 16));
      }
      // swapped QK^T: s[i] = S^T[kv = kv0+i*16+kb*4+j][q]
      f32x4 s[4] = {};
      __builtin_amdgcn_s_setprio(1);
#pragma unroll
      for (int i = 0; i < 4; ++i) {
        s[i] = MFMA16(kf[i * 2 + 0], qf0, s[i]);
        s[i] = MFMA16(kf[i * 2 + 1], qf1, s[i]);
      }
      __builtin_amdgcn_s_setprio(0);

      // V fragments: issue now, consumed after softmax (latency hidden)
      bf16x8 vf[8];
#pragma unroll
      for (int i = 0; i < 4; ++i) {
        const int row = i * 16 + l16;
#pragma unroll
        for (int kc = 0; kc < 2; ++kc)
          vf[i * 2 + kc] = ldv8(Vb + row * 128 + (((kc * 4 + kb) ^ (row & 7)) * 16));
      }

      // causal mask + online softmax (row = this lane's q, 2 shuffles/reduce)
      float mx = -1e30f;
#pragma unroll
      for (int i = 0; i < 4; ++i)
#pragma unroll
        for (int j = 0; j < 4; ++j) {
          const int kv = kv0 + i * 16 + kb * 4 + j;
          const float v = (kv <= q) ? s[i][j] : -1e30f;
          s[i][j] = v;
          mx = fmaxf(mx, v);
        }
      mx = fmaxf(mx, __shfl_xor(mx, 16));
      mx = fmaxf(mx, __shfl_xor(mx, 32));
      const float mn = fmaxf(m_r, mx);
      const float sc = __expf(m_r - mn);
      float ss = 0.f;
      bf16x4 pw[4];
#pragma unroll
      for (int i = 0; i < 4; ++i)
#pragma unroll
        for (int j = 0; j < 4; ++j) {
          const float p = __expf(s[i][j] - mn);
          ss += p;
          pw[i][j] = (bf16_t)p;
        }
      ss += __shfl_xor(ss, 16);
      ss += __shfl_xor(ss, 32);
      l_r = l_r * sc + ss;
      m_r = mn;
#pragma unroll
      for (int i = 0; i < 4; ++i) {
        o[i][0] *= sc; o[i][1] *= sc; o[i][2] *= sc; o[i][3] *= sc;
      }

      // P^T round-trip, wave-private, 16B-chunk XOR swizzle (2-way = free)
#pragma unroll
      for (int i = 0; i < 4; ++i) {
        const int phys = (i * 2 + (kb >> 1)) ^ l8;
        *reinterpret_cast<bf16x4*>(Pw + l16 * 128 + phys * 16 + (kb & 1) * 8) = pw[i];
      }
      const bf16x8 pb0 = ldv8(Pw + l16 * 128 + ((kb ^ l8) * 16));
      const bf16x8 pb1 = ldv8(Pw + l16 * 128 + (((4 + kb) ^ l8) * 16));

      // PV: o[i] = O^T[d = i*16+kb*4+j][q]
      __builtin_amdgcn_s_setprio(1);
#pragma unroll
      for (int i = 0; i < 4; ++i) {
        o[i] = MFMA16(vf[i * 2 + 0], pb0, o[i]);
        o[i] = MFMA16(vf[i * 2 + 1], pb1, o[i]);
      }
      __builtin_amdgcn_s_setprio(0);

      // single drain+barrier per tile: next buffer staged, this one consumed
      asm volatile("s_waitcnt vmcnt(0)" ::: "memory");
      __builtin_amdgcn_s_barrier();
      __builtin_amdgcn_sched_barrier(0);
      cur ^= 1;
    }

    const float inv = 1.0f / l_r;
    bf16_t* yrow = Yg + ((size_t)(b * 2048 + q)) * 1024 + h * 64;
#pragma unroll
    for (int i = 0; i < 4; ++i) {
      bf16x4 yv;
      yv[0] = (bf16_t)(o[i][0] * inv);
      yv[1] = (bf16_t)(o[i][1] * inv);
      yv[2] = (bf16_t)(o[i][2] * inv);
      yv[3] = (bf16_t)(o[i][3] * inv);
      *reinterpret_cast<bf16x4*>(yrow + i * 16 + kb * 4) = yv;
    }
  }
}

// --------------------------------------------------------------- launch ---
extern "C" void kernel_launch(void* const* d_in, const int* in_sizes, int n_in,
                              void* d_out, int out_size, void* d_ws, size_t ws_size,
                              hipStream_t stream) {
  const float* x = (const float*)d_in[0];
  const float* W_attn = (const float*)d_in[1];
  const float* b_attn = (const float*)d_in[2];
  const float* W_proj = (const float*)d_in[3];
  const float* b_proj = (const float*)d_in[4];
  float* out = (float*)d_out;

  char* ws = (char*)d_ws;
  bf16_t* xb  = (bf16_t*)(ws + 0);
  bf16_t* WaT = (bf16_t*)(ws + 16777216);
  bf16_t* WpT = (bf16_t*)(ws + 23068672);
  bf16_t* Qb  = (bf16_t*)(ws + 25165824);
  bf16_t* Kb  = (bf16_t*)(ws + 41943040);
  bf16_t* Vt  = (bf16_t*)(ws + 58720256);
  bf16_t* Yb  = (bf16_t*)(ws + 75497472);

  cvt_f32_bf16<<<8192, 256, 0, stream>>>(x, xb, 8192 * 1024 / 4);
  transpose_cvt<<<dim3(96, 32), dim3(32, 8), 0, stream>>>(W_attn, WaT, 1024, 3072);
  transpose_cvt<<<dim3(32, 32), dim3(32, 8), 0, stream>>>(W_proj, WpT, 1024, 1024);

  gemm_bf16<0><<<dim3(24, 64), 256, 0, stream>>>(xb, WaT, b_attn, 8192, 3072, 1024,
                                                 Qb, Kb, Vt, nullptr);

  attn_fwd<<<1024, 256, 0, stream>>>(Qb, Kb, Vt, Yb);

  gemm_bf16<1><<<dim3(8, 64), 256, 0, stream>>>(Yb, WpT, b_proj, 8192, 1024, 1024,
                                                nullptr, nullptr, nullptr, out);
}

// Round 4
// 203.584 us; speedup vs baseline: 2.9776x; 1.0365x over previous
//
#include <hip/hip_runtime.h>

// ---------------------------------------------------------------------------
// CausalSelfAttention forward on MI355X (gfx950).
// B=4, T=2048, C=1024, H=16, hs=64.
// Pipeline: [cvt x->bf16, transpose W's] -> QKV GEMM (bf16 MFMA) ->
//           flash attention (swapped-QK, 24KB LDS, base-2 softmax) -> proj.
// Workspace layout (bytes):
//   xb    @ 0         : 8192x1024 bf16           (16,777,216)
//   WaT   @ 16777216  : 3072x1024 bf16           ( 6,291,456)
//   WpT   @ 23068672  : 1024x1024 bf16           ( 2,097,152)
//   Q     @ 25165824  : [64][2048][64] bf16      (pre-scaled by log2e/8)
//   K     @ 41943040  : [64][2048][64] bf16
//   Vt    @ 58720256  : [64][64][2048] bf16      (V transposed per head)
//   Y     @ 75497472  : 8192x1024 bf16
// ---------------------------------------------------------------------------

typedef __bf16 bf16_t;
typedef __bf16 bf16x8 __attribute__((ext_vector_type(8)));
typedef __bf16 bf16x4 __attribute__((ext_vector_type(4)));
typedef float  f32x4  __attribute__((ext_vector_type(4)));

#define MFMA16(a, b, c) __builtin_amdgcn_mfma_f32_16x16x32_bf16((a), (b), (c), 0, 0, 0)

static __device__ __forceinline__ void gld_lds16(const bf16_t* g, void* l) {
  __builtin_amdgcn_global_load_lds(
      (const __attribute__((address_space(1))) void*)(const void*)g,
      (__attribute__((address_space(3))) void*)l, 16, 0, 0);
}

static __device__ __forceinline__ bf16x8 ldv8(const void* p) {
  return *reinterpret_cast<const bf16x8*>(p);
}

static __device__ __forceinline__ float exp2_hw(float x) {
  float r;
  asm("v_exp_f32 %0, %1" : "=v"(r) : "v"(x));
  return r;
}

// ---------------------------------------------------------------- prep ----
__global__ __launch_bounds__(256) void cvt_f32_bf16(const float* __restrict__ in,
                                                    bf16_t* __restrict__ out, int n4) {
  int i = blockIdx.x * 256 + threadIdx.x;
  if (i < n4) {
    float4 v = reinterpret_cast<const float4*>(in)[i];
    bf16x4 o;
    o[0] = (bf16_t)v.x; o[1] = (bf16_t)v.y; o[2] = (bf16_t)v.z; o[3] = (bf16_t)v.w;
    reinterpret_cast<bf16x4*>(out)[i] = o;
  }
}

// in [Kd][Nd] f32  ->  out [Nd][Kd] bf16
__global__ __launch_bounds__(256) void transpose_cvt(const float* __restrict__ in,
                                                     bf16_t* __restrict__ out,
                                                     int Kd, int Nd) {
  __shared__ float tile[32][33];
  int tx = threadIdx.x, ty = threadIdx.y;
  int n0 = blockIdx.x * 32, k0 = blockIdx.y * 32;
#pragma unroll
  for (int i = 0; i < 4; ++i)
    tile[ty + i * 8][tx] = in[(size_t)(k0 + ty + i * 8) * Nd + (n0 + tx)];
  __syncthreads();
#pragma unroll
  for (int i = 0; i < 4; ++i)
    out[(size_t)(n0 + ty + i * 8) * Kd + (k0 + tx)] = (bf16_t)tile[tx][ty + i * 8];
}

// ---------------------------------------------------------------- GEMM ----
// 128x128 tile, BK=64, 4 waves, gld_lds staging w/ source-side XOR swizzle.
// XCD-bijective block swizzle (nwg % 8 == 0).
// MODE 0: scatter qkv -> Q (x log2e/8), K, Vt. MODE 1: f32 out.
template <int MODE>
__global__ __launch_bounds__(256) void gemm_bf16(
    const bf16_t* __restrict__ A, const bf16_t* __restrict__ Bt,
    const float* __restrict__ bias, int M, int N, int K,
    bf16_t* __restrict__ Qo, bf16_t* __restrict__ Ko, bf16_t* __restrict__ Vt,
    float* __restrict__ Co) {
  __shared__ alignas(16) char lds[32768];

  const int tid = threadIdx.x;
  const int wave = tid >> 6, lane = tid & 63;
  const int wm = wave >> 1, wn = wave & 1;
  const int l16 = lane & 15, kb = lane >> 4;

  // XCD-aware bijective swizzle of the linearized block id
  const int nbx = gridDim.x;
  const int lb = blockIdx.y * nbx + blockIdx.x;
  const int cpx = (nbx * gridDim.y) >> 3;
  const int sw = (lb & 7) * cpx + (lb >> 3);
  const int tm0 = (sw / nbx) * 128, tn0 = (sw % nbx) * 128;

  const int srow = wave * 8 + (lane >> 3);
  const int sp = lane & 7;

  f32x4 acc[4][4] = {};

  for (int k0 = 0; k0 < K; k0 += 64) {
    __syncthreads();
#pragma unroll
    for (int inst = 0; inst < 4; ++inst) {
      const int row = inst * 32 + srow;
      const int chunk = (sp ^ (row & 7)) * 8;
      gld_lds16(A + (size_t)(tm0 + row) * K + k0 + chunk,
                &lds[inst * 4096 + wave * 1024]);
      gld_lds16(Bt + (size_t)(tn0 + row) * K + k0 + chunk,
                &lds[16384 + inst * 4096 + wave * 1024]);
    }
    __syncthreads();
#pragma unroll
    for (int kc = 0; kc < 2; ++kc) {
      bf16x8 af[4], bfr[4];
#pragma unroll
      for (int mi = 0; mi < 4; ++mi) {
        const int row = wm * 64 + mi * 16 + l16;
        const int slot = (kc * 4 + kb) ^ (row & 7);
        af[mi] = ldv8(&lds[row * 128 + slot * 16]);
      }
#pragma unroll
      for (int ni = 0; ni < 4; ++ni) {
        const int row = wn * 64 + ni * 16 + l16;
        const int slot = (kc * 4 + kb) ^ (row & 7);
        bfr[ni] = ldv8(&lds[16384 + row * 128 + slot * 16]);
      }
#pragma unroll
      for (int mi = 0; mi < 4; ++mi)
#pragma unroll
        for (int ni = 0; ni < 4; ++ni)
          acc[mi][ni] = MFMA16(af[mi], bfr[ni], acc[mi][ni]);
    }
  }

#pragma unroll
  for (int ni = 0; ni < 4; ++ni) {
    const int n = tn0 + wn * 64 + ni * 16 + l16;
    const float bv = bias[n];
#pragma unroll
    for (int mi = 0; mi < 4; ++mi) {
#pragma unroll
      for (int j = 0; j < 4; ++j) {
        const int m = tm0 + wm * 64 + mi * 16 + kb * 4 + j;
        const float v = acc[mi][ni][j] + bv;
        if constexpr (MODE == 0) {
          const int which = n >> 10, hn = n & 1023;
          const int h = hn >> 6, d = hn & 63;
          const int b = m >> 11, t = m & 2047;
          const size_t bh = (size_t)(b * 16 + h);
          if (which == 0)  // fold 1/sqrt(hs) * log2(e) for base-2 softmax
            Qo[(bh * 2048 + t) * 64 + d] = (bf16_t)(v * 0.18033688011112042f);
          else if (which == 1)
            Ko[(bh * 2048 + t) * 64 + d] = (bf16_t)v;
          else
            Vt[(bh * 64 + d) * 2048 + t] = (bf16_t)v;
        } else {
          Co[(size_t)m * N + n] = v;
        }
      }
    }
  }
}

// ----------------------------------------------------------- attention ----
// 4 waves/block, 16 q-rows/wave (swapped-QK: lane owns one q-row), KVBLK=64.
// LDS 24KB: K dbuf 2x8KB @0, V single 8KB @16384. P^T scratch reuses the
// DEAD K[cur] region (K[cur] fully in regs before the mid-iter barrier).
// Mid-iter barrier is lgkmcnt-only (vmcnt stays in flight -> K prefetch
// pipelined); V restaged after it. Base-2 softmax (Q pre-scaled by log2e/8),
// diagonal-only masking, defer-max (THR=8 log2). Uniform 33 trips/block via
// q-tile pairing; heads grouped 8-per-XCD.
__global__ __launch_bounds__(256) void attn_fwd(const bf16_t* __restrict__ Qg,
                                                const bf16_t* __restrict__ Kg,
                                                const bf16_t* __restrict__ Vtg,
                                                bf16_t* __restrict__ Yg) {
  __shared__ alignas(16) char lds[24576];

  const int tid = threadIdx.x;
  const int wave = tid >> 6, lane = tid & 63;
  const int l16 = lane & 15, kb = lane >> 4;
  const int l8 = l16 & 7;
  const float NEG_INF = -__builtin_inff();

  const int n = blockIdx.x;                    // 1024 blocks
  const int bh = (n & 7) * 8 + ((n >> 3) & 7); // 8 heads per XCD
  const int pp = n >> 6;                       // pair index [0,16)
  const size_t base = (size_t)bh * (2048 * 64);
  const int b = bh >> 4, h = bh & 15;

  const int srow = tid >> 3;
  const int schunk = (tid & 7) ^ (srow & 7);
  const bf16_t* Ksrc = Kg + base + (size_t)srow * 64 + schunk * 8;
  const bf16_t* Vsrc = Vtg + base + (size_t)srow * 2048 + schunk * 8;

  auto stageK = [&](int buf, int kv0) {
    char* kd = lds + buf * 8192 + wave * 1024;
    const bf16_t* ks = Ksrc + (size_t)kv0 * 64;
    gld_lds16(ks, kd);
    gld_lds16(ks + 2048, kd + 4096);
  };
  auto stageV = [&](int kv0) {
    char* vd = lds + 16384 + wave * 1024;
    const bf16_t* vs = Vsrc + kv0;
    gld_lds16(vs, vd);
    gld_lds16(vs + 65536, vd + 4096);
  };

  for (int pass = 0; pass < 2; ++pass) {
    const int qt = pass ? (31 - pp) : pp;      // q-tile index [0,32)
    const int q0 = qt * 64 + wave * 16;
    const int q = q0 + l16;                    // this lane's q-row
    const int trips = qt + 1;

    const bf16x8 qf0 = ldv8(Qg + base + (size_t)q * 64 + kb * 8);
    const bf16x8 qf1 = ldv8(Qg + base + (size_t)q * 64 + 32 + kb * 8);

    f32x4 o[4] = {};
    float m_r = NEG_INF, l_r = 0.f;

    stageK(0, 0);
    stageV(0);
    asm volatile("s_waitcnt vmcnt(0)" ::: "memory");
    __builtin_amdgcn_s_barrier();
    __builtin_amdgcn_sched_barrier(0);

    int cur = 0;
    for (int t = 0; t < trips; ++t) {
      const int kv0 = t * 64;
      const bool more = (t + 1 < trips);
      if (more) stageK(cur ^ 1, kv0 + 64);     // async, drains at iter end

      const char* Kb = lds + cur * 8192;
      const char* Vb = lds + 16384;

      bf16x8 kf[8];
#pragma unroll
      for (int i = 0; i < 4; ++i) {
        const int row = i * 16 + l16;
#pragma unroll
        for (int kc = 0; kc < 2; ++kc)
          kf[i * 2 + kc] = ldv8(Kb + row * 128 + (((kc * 4 + kb) ^ (row & 7)) * 16));
      }
      f32x4 s[4] = {};
      __builtin_amdgcn_s_setprio(1);
#pragma unroll
      for (int i = 0; i < 4; ++i) {
        s[i] = MFMA16(kf[i * 2 + 0], qf0, s[i]);
        s[i] = MFMA16(kf[i * 2 + 1], qf1, s[i]);
      }
      __builtin_amdgcn_s_setprio(0);

      bf16x8 vf[8];
#pragma unroll
      for (int i = 0; i < 4; ++i) {
        const int row = i * 16 + l16;
#pragma unroll
        for (int kc = 0; kc < 2; ++kc)
          vf[i * 2 + kc] = ldv8(Vb + row * 128 + (((kc * 4 + kb) ^ (row & 7)) * 16));
      }

      // --- online softmax in base-2 ------------------------------------
      float pm[4];
      if (t == qt) {  // diagonal tile: apply causal mask (wave-uniform branch)
#pragma unroll
        for (int i = 0; i < 4; ++i) {
          f32x4 sv = s[i];
#pragma unroll
          for (int j = 0; j < 4; ++j)
            if (kv0 + i * 16 + kb * 4 + j > q) sv[j] = NEG_INF;
          s[i] = sv;
          pm[i] = fmaxf(fmaxf(sv[0], sv[1]), fmaxf(sv[2], sv[3]));
        }
      } else {
#pragma unroll
        for (int i = 0; i < 4; ++i)
          pm[i] = fmaxf(fmaxf(s[i][0], s[i][1]), fmaxf(s[i][2], s[i][3]));
      }
      float mx = fmaxf(fmaxf(pm[0], pm[1]), fmaxf(pm[2], pm[3]));
      mx = fmaxf(mx, __shfl_xor(mx, 16));
      mx = fmaxf(mx, __shfl_xor(mx, 32));

      if (__any(mx > m_r + 8.0f)) {            // defer-max: rescale rarely
        const float mn = fmaxf(m_r, mx);
        const float sc = exp2_hw(m_r - mn);
        l_r *= sc;
#pragma unroll
        for (int i = 0; i < 4; ++i) {
          o[i][0] *= sc; o[i][1] *= sc; o[i][2] *= sc; o[i][3] *= sc;
        }
        m_r = mn;
      }

      float ss = 0.f;
      bf16x4 pw[4];
#pragma unroll
      for (int i = 0; i < 4; ++i)
#pragma unroll
        for (int j = 0; j < 4; ++j) {
          const float p = exp2_hw(s[i][j] - m_r);
          ss += p;
          pw[i][j] = (bf16_t)p;
        }
      ss += __shfl_xor(ss, 16);
      ss += __shfl_xor(ss, 32);
      l_r += ss;

      // --- mid-iter barrier: lgkm-only (vmcnt prefetch stays in flight) --
      asm volatile("s_waitcnt lgkmcnt(0)" ::: "memory");
      __builtin_amdgcn_s_barrier();
      __builtin_amdgcn_sched_barrier(0);
      if (more) stageV(kv0 + 64);              // V buffer now safe to overwrite

      // P^T through the dead K[cur] region (wave-private 2KB slice)
      char* Pw = lds + cur * 8192 + wave * 2048;
#pragma unroll
      for (int i = 0; i < 4; ++i) {
        const int phys = (i * 2 + (kb >> 1)) ^ l8;
        *reinterpret_cast<bf16x4*>(Pw + l16 * 128 + phys * 16 + (kb & 1) * 8) = pw[i];
      }
      const bf16x8 pb0 = ldv8(Pw + l16 * 128 + ((kb ^ l8) * 16));
      const bf16x8 pb1 = ldv8(Pw + l16 * 128 + (((4 + kb) ^ l8) * 16));

      __builtin_amdgcn_s_setprio(1);
#pragma unroll
      for (int i = 0; i < 4; ++i) {
        o[i] = MFMA16(vf[i * 2 + 0], pb0, o[i]);
        o[i] = MFMA16(vf[i * 2 + 1], pb1, o[i]);
      }
      __builtin_amdgcn_s_setprio(0);

      asm volatile("s_waitcnt vmcnt(0)" ::: "memory");
      __builtin_amdgcn_s_barrier();
      __builtin_amdgcn_sched_barrier(0);
      cur ^= 1;
    }

    const float inv = 1.0f / l_r;
    bf16_t* yrow = Yg + ((size_t)(b * 2048 + q)) * 1024 + h * 64;
#pragma unroll
    for (int i = 0; i < 4; ++i) {
      bf16x4 yv;
      yv[0] = (bf16_t)(o[i][0] * inv);
      yv[1] = (bf16_t)(o[i][1] * inv);
      yv[2] = (bf16_t)(o[i][2] * inv);
      yv[3] = (bf16_t)(o[i][3] * inv);
      *reinterpret_cast<bf16x4*>(yrow + i * 16 + kb * 4) = yv;
    }
  }
}

// --------------------------------------------------------------- launch ---
extern "C" void kernel_launch(void* const* d_in, const int* in_sizes, int n_in,
                              void* d_out, int out_size, void* d_ws, size_t ws_size,
                              hipStream_t stream) {
  const float* x = (const float*)d_in[0];
  const float* W_attn = (const float*)d_in[1];
  const float* b_attn = (const float*)d_in[2];
  const float* W_proj = (const float*)d_in[3];
  const float* b_proj = (const float*)d_in[4];
  float* out = (float*)d_out;

  char* ws = (char*)d_ws;
  bf16_t* xb  = (bf16_t*)(ws + 0);
  bf16_t* WaT = (bf16_t*)(ws + 16777216);
  bf16_t* WpT = (bf16_t*)(ws + 23068672);
  bf16_t* Qb  = (bf16_t*)(ws + 25165824);
  bf16_t* Kb  = (bf16_t*)(ws + 41943040);
  bf16_t* Vt  = (bf16_t*)(ws + 58720256);
  bf16_t* Yb  = (bf16_t*)(ws + 75497472);

  cvt_f32_bf16<<<8192, 256, 0, stream>>>(x, xb, 8192 * 1024 / 4);
  transpose_cvt<<<dim3(96, 32), dim3(32, 8), 0, stream>>>(W_attn, WaT, 1024, 3072);
  transpose_cvt<<<dim3(32, 32), dim3(32, 8), 0, stream>>>(W_proj, WpT, 1024, 1024);

  gemm_bf16<0><<<dim3(24, 64), 256, 0, stream>>>(xb, WaT, b_attn, 8192, 3072, 1024,
                                                 Qb, Kb, Vt, nullptr);

  attn_fwd<<<1024, 256, 0, stream>>>(Qb, Kb, Vt, Yb);

  gemm_bf16<1><<<dim3(8, 64), 256, 0, stream>>>(Yb, WpT, b_proj, 8192, 1024, 1024,
                                                nullptr, nullptr, nullptr, out);
}

// Round 5
// 202.060 us; speedup vs baseline: 3.0000x; 1.0075x over previous
//
#include <hip/hip_runtime.h>

// ---------------------------------------------------------------------------
// CausalSelfAttention forward on MI355X (gfx950).
// B=4, T=2048, C=1024, H=16, hs=64.
// Pipeline: [cvt x->bf16, transpose W's] -> QKV GEMM (bf16 MFMA) ->
//           flash attention (swapped-QK, pair-merged kv sweep) -> proj.
// Workspace layout (bytes):
//   xb    @ 0         : 8192x1024 bf16           (16,777,216)
//   WaT   @ 16777216  : 3072x1024 bf16           ( 6,291,456)
//   WpT   @ 23068672  : 1024x1024 bf16           ( 2,097,152)
//   Q     @ 25165824  : [64][2048][64] bf16      (pre-scaled by log2e/8)
//   K     @ 41943040  : [64][2048][64] bf16
//   Vt    @ 58720256  : [64][64][2048] bf16      (V transposed per head)
//   Y     @ 75497472  : 8192x1024 bf16
// ---------------------------------------------------------------------------

typedef __bf16 bf16_t;
typedef __bf16 bf16x8 __attribute__((ext_vector_type(8)));
typedef __bf16 bf16x4 __attribute__((ext_vector_type(4)));
typedef float  f32x4  __attribute__((ext_vector_type(4)));

#define MFMA16(a, b, c) __builtin_amdgcn_mfma_f32_16x16x32_bf16((a), (b), (c), 0, 0, 0)

static __device__ __forceinline__ void gld_lds16(const bf16_t* g, void* l) {
  __builtin_amdgcn_global_load_lds(
      (const __attribute__((address_space(1))) void*)(const void*)g,
      (__attribute__((address_space(3))) void*)l, 16, 0, 0);
}

static __device__ __forceinline__ bf16x8 ldv8(const void* p) {
  return *reinterpret_cast<const bf16x8*>(p);
}

static __device__ __forceinline__ float exp2_hw(float x) {
  float r;
  asm("v_exp_f32 %0, %1" : "=v"(r) : "v"(x));
  return r;
}

// ---------------------------------------------------------------- prep ----
__global__ __launch_bounds__(256) void cvt_f32_bf16(const float* __restrict__ in,
                                                    bf16_t* __restrict__ out, int n4) {
  int i = blockIdx.x * 256 + threadIdx.x;
  if (i < n4) {
    float4 v = reinterpret_cast<const float4*>(in)[i];
    bf16x4 o;
    o[0] = (bf16_t)v.x; o[1] = (bf16_t)v.y; o[2] = (bf16_t)v.z; o[3] = (bf16_t)v.w;
    reinterpret_cast<bf16x4*>(out)[i] = o;
  }
}

// in [Kd][Nd] f32  ->  out [Nd][Kd] bf16
__global__ __launch_bounds__(256) void transpose_cvt(const float* __restrict__ in,
                                                     bf16_t* __restrict__ out,
                                                     int Kd, int Nd) {
  __shared__ float tile[32][33];
  int tx = threadIdx.x, ty = threadIdx.y;
  int n0 = blockIdx.x * 32, k0 = blockIdx.y * 32;
#pragma unroll
  for (int i = 0; i < 4; ++i)
    tile[ty + i * 8][tx] = in[(size_t)(k0 + ty + i * 8) * Nd + (n0 + tx)];
  __syncthreads();
#pragma unroll
  for (int i = 0; i < 4; ++i)
    out[(size_t)(n0 + ty + i * 8) * Kd + (k0 + tx)] = (bf16_t)tile[tx][ty + i * 8];
}

// ---------------------------------------------------------------- GEMM ----
// 128x128 tile, BK=64, 4 waves, gld_lds staging w/ source-side XOR swizzle.
// XCD-bijective block swizzle (nwg % 8 == 0).
// MODE 0: scatter qkv -> Q (x log2e/8), K, Vt. MODE 1: f32 out.
template <int MODE>
__global__ __launch_bounds__(256) void gemm_bf16(
    const bf16_t* __restrict__ A, const bf16_t* __restrict__ Bt,
    const float* __restrict__ bias, int M, int N, int K,
    bf16_t* __restrict__ Qo, bf16_t* __restrict__ Ko, bf16_t* __restrict__ Vt,
    float* __restrict__ Co) {
  __shared__ alignas(16) char lds[32768];

  const int tid = threadIdx.x;
  const int wave = tid >> 6, lane = tid & 63;
  const int wm = wave >> 1, wn = wave & 1;
  const int l16 = lane & 15, kb = lane >> 4;

  const int nbx = gridDim.x;
  const int lb = blockIdx.y * nbx + blockIdx.x;
  const int cpx = (nbx * gridDim.y) >> 3;
  const int sw = (lb & 7) * cpx + (lb >> 3);
  const int tm0 = (sw / nbx) * 128, tn0 = (sw % nbx) * 128;

  const int srow = wave * 8 + (lane >> 3);
  const int sp = lane & 7;

  f32x4 acc[4][4] = {};

  for (int k0 = 0; k0 < K; k0 += 64) {
    __syncthreads();
#pragma unroll
    for (int inst = 0; inst < 4; ++inst) {
      const int row = inst * 32 + srow;
      const int chunk = (sp ^ (row & 7)) * 8;
      gld_lds16(A + (size_t)(tm0 + row) * K + k0 + chunk,
                &lds[inst * 4096 + wave * 1024]);
      gld_lds16(Bt + (size_t)(tn0 + row) * K + k0 + chunk,
                &lds[16384 + inst * 4096 + wave * 1024]);
    }
    __syncthreads();
#pragma unroll
    for (int kc = 0; kc < 2; ++kc) {
      bf16x8 af[4], bfr[4];
#pragma unroll
      for (int mi = 0; mi < 4; ++mi) {
        const int row = wm * 64 + mi * 16 + l16;
        const int slot = (kc * 4 + kb) ^ (row & 7);
        af[mi] = ldv8(&lds[row * 128 + slot * 16]);
      }
#pragma unroll
      for (int ni = 0; ni < 4; ++ni) {
        const int row = wn * 64 + ni * 16 + l16;
        const int slot = (kc * 4 + kb) ^ (row & 7);
        bfr[ni] = ldv8(&lds[16384 + row * 128 + slot * 16]);
      }
#pragma unroll
      for (int mi = 0; mi < 4; ++mi)
#pragma unroll
        for (int ni = 0; ni < 4; ++ni)
          acc[mi][ni] = MFMA16(af[mi], bfr[ni], acc[mi][ni]);
    }
  }

#pragma unroll
  for (int ni = 0; ni < 4; ++ni) {
    const int n = tn0 + wn * 64 + ni * 16 + l16;
    const float bv = bias[n];
#pragma unroll
    for (int mi = 0; mi < 4; ++mi) {
#pragma unroll
      for (int j = 0; j < 4; ++j) {
        const int m = tm0 + wm * 64 + mi * 16 + kb * 4 + j;
        const float v = acc[mi][ni][j] + bv;
        if constexpr (MODE == 0) {
          const int which = n >> 10, hn = n & 1023;
          const int h = hn >> 6, d = hn & 63;
          const int b = m >> 11, t = m & 2047;
          const size_t bh = (size_t)(b * 16 + h);
          if (which == 0)  // fold 1/sqrt(hs) * log2(e) for base-2 softmax
            Qo[(bh * 2048 + t) * 64 + d] = (bf16_t)(v * 0.18033688011112042f);
          else if (which == 1)
            Ko[(bh * 2048 + t) * 64 + d] = (bf16_t)v;
          else
            Vt[(bh * 64 + d) * 2048 + t] = (bf16_t)v;
        } else {
          Co[(size_t)m * N + n] = v;
        }
      }
    }
  }
}

// ----------------------------------------------------------- attention ----
// Pair-merged sweep: each block owns q-tiles A=pp and B=31-pp and sweeps kv
// tiles 0..31-pp ONCE, applying each staged K/V tile to BOTH q-tiles
// (A active while t <= pp). kf/vf ds_reads, staging and the single
// end-of-iter barrier are amortized over both tiles; the two softmaxes are
// independent -> 2x VALU ILP. K and V both double-buffered (no mid barrier);
// P roundtrip is wave-private (no barrier). LDS 48KB.
// Swapped-QK: lane owns one q-row per tile; base-2 softmax (Q pre-scaled by
// log2e/8), diagonal-only masking, defer-max. Heads grouped 8-per-XCD.
__global__ __launch_bounds__(256) void attn_fwd(const bf16_t* __restrict__ Qg,
                                                const bf16_t* __restrict__ Kg,
                                                const bf16_t* __restrict__ Vtg,
                                                bf16_t* __restrict__ Yg) {
  __shared__ alignas(16) char lds[49152];  // K 2x8K @0, V 2x8K @16384, P 2x8K @32768

  const int tid = threadIdx.x;
  const int wave = tid >> 6, lane = tid & 63;
  const int l16 = lane & 15, kb = lane >> 4;
  const int l8 = l16 & 7;
  const float NEG_INF = -__builtin_inff();

  const int n = blockIdx.x;                    // 1024 blocks
  const int bh = (n & 7) * 8 + ((n >> 3) & 7); // 8 heads per XCD
  const int pp = n >> 6;                       // pair index [0,16)
  const size_t base = (size_t)bh * (2048 * 64);
  const int b = bh >> 4, h = bh & 15;

  const int srow = tid >> 3;
  const int schunk = (tid & 7) ^ (srow & 7);
  const bf16_t* Ksrc = Kg + base + (size_t)srow * 64 + schunk * 8;
  const bf16_t* Vsrc = Vtg + base + (size_t)srow * 2048 + schunk * 8;

  auto stageK = [&](int buf, int kv0) {
    char* kd = lds + buf * 8192 + wave * 1024;
    const bf16_t* ks = Ksrc + (size_t)kv0 * 64;
    gld_lds16(ks, kd);
    gld_lds16(ks + 2048, kd + 4096);
  };
  auto stageV = [&](int buf, int kv0) {
    char* vd = lds + 16384 + buf * 8192 + wave * 1024;
    const bf16_t* vs = Vsrc + kv0;
    gld_lds16(vs, vd);
    gld_lds16(vs + 65536, vd + 4096);
  };

  const int qtA = pp, qtB = 31 - pp;
  const int trips = 32 - pp;
  const int qA = qtA * 64 + wave * 16 + l16;
  const int qB = qtB * 64 + wave * 16 + l16;

  const bf16x8 qfA0 = ldv8(Qg + base + (size_t)qA * 64 + kb * 8);
  const bf16x8 qfA1 = ldv8(Qg + base + (size_t)qA * 64 + 32 + kb * 8);
  const bf16x8 qfB0 = ldv8(Qg + base + (size_t)qB * 64 + kb * 8);
  const bf16x8 qfB1 = ldv8(Qg + base + (size_t)qB * 64 + 32 + kb * 8);

  f32x4 oA[4] = {}, oB[4] = {};
  float mA = NEG_INF, lA = 0.f, mB = NEG_INF, lB = 0.f;

  // online softmax in base-2 on one tile-state
  auto online_sm = [&](f32x4 (&s)[4], bf16x4 (&pw)[4], f32x4 (&o)[4],
                       float& m_r, float& l_r, int q, int kv0, bool diag) {
    float pm[4];
#pragma unroll
    for (int i = 0; i < 4; ++i) {
      f32x4 sv = s[i];
      if (diag) {
#pragma unroll
        for (int j = 0; j < 4; ++j)
          if (kv0 + i * 16 + kb * 4 + j > q) sv[j] = NEG_INF;
        s[i] = sv;
      }
      pm[i] = fmaxf(fmaxf(sv[0], sv[1]), fmaxf(sv[2], sv[3]));
    }
    float mx = fmaxf(fmaxf(pm[0], pm[1]), fmaxf(pm[2], pm[3]));
    mx = fmaxf(mx, __shfl_xor(mx, 16));
    mx = fmaxf(mx, __shfl_xor(mx, 32));
    if (__any(mx > m_r + 8.0f)) {              // defer-max: rescale rarely
      const float mn = fmaxf(m_r, mx);
      const float sc = exp2_hw(m_r - mn);
      l_r *= sc;
#pragma unroll
      for (int i = 0; i < 4; ++i) {
        o[i][0] *= sc; o[i][1] *= sc; o[i][2] *= sc; o[i][3] *= sc;
      }
      m_r = mn;
    }
    float ss = 0.f;
#pragma unroll
    for (int i = 0; i < 4; ++i)
#pragma unroll
      for (int j = 0; j < 4; ++j) {
        const float p = exp2_hw(s[i][j] - m_r);
        ss += p;
        pw[i][j] = (bf16_t)p;
      }
    ss += __shfl_xor(ss, 16);
    ss += __shfl_xor(ss, 32);
    l_r += ss;
  };

  // wave-private P^T roundtrip (16B-chunk XOR swizzle; verified r3/r4)
  auto p_roundtrip = [&](char* Pw, const bf16x4 (&pw)[4], bf16x8& pb0, bf16x8& pb1) {
#pragma unroll
    for (int i = 0; i < 4; ++i) {
      const int phys = (i * 2 + (kb >> 1)) ^ l8;
      *reinterpret_cast<bf16x4*>(Pw + l16 * 128 + phys * 16 + (kb & 1) * 8) = pw[i];
    }
    pb0 = ldv8(Pw + l16 * 128 + ((kb ^ l8) * 16));
    pb1 = ldv8(Pw + l16 * 128 + (((4 + kb) ^ l8) * 16));
  };

  char* PA = lds + 32768 + wave * 2048;
  char* PB = lds + 40960 + wave * 2048;

  stageK(0, 0);
  stageV(0, 0);
  asm volatile("s_waitcnt vmcnt(0)" ::: "memory");
  __builtin_amdgcn_s_barrier();
  __builtin_amdgcn_sched_barrier(0);

  int cur = 0;
  for (int t = 0; t < trips; ++t) {
    const int kv0 = t * 64;
    const bool more = (t + 1 < trips);
    if (more) {
      stageK(cur ^ 1, kv0 + 64);               // async, drains at iter end
      stageV(cur ^ 1, kv0 + 64);
    }
    const bool aAct = (t <= pp);               // wave-uniform

    const char* Kb = lds + cur * 8192;
    const char* Vb = lds + 16384 + cur * 8192;

    bf16x8 kf[8];
#pragma unroll
    for (int i = 0; i < 4; ++i) {
      const int row = i * 16 + l16;
#pragma unroll
      for (int kc = 0; kc < 2; ++kc)
        kf[i * 2 + kc] = ldv8(Kb + row * 128 + (((kc * 4 + kb) ^ (row & 7)) * 16));
    }

    f32x4 sA[4] = {}, sB[4] = {};
    __builtin_amdgcn_s_setprio(1);
#pragma unroll
    for (int i = 0; i < 4; ++i) {
      sB[i] = MFMA16(kf[i * 2 + 0], qfB0, sB[i]);
      sB[i] = MFMA16(kf[i * 2 + 1], qfB1, sB[i]);
    }
    if (aAct) {
#pragma unroll
      for (int i = 0; i < 4; ++i) {
        sA[i] = MFMA16(kf[i * 2 + 0], qfA0, sA[i]);
        sA[i] = MFMA16(kf[i * 2 + 1], qfA1, sA[i]);
      }
    }
    __builtin_amdgcn_s_setprio(0);

    // V fragments shared by both PV steps (independent of softmax -> overlap)
    bf16x8 vf[8];
#pragma unroll
    for (int i = 0; i < 4; ++i) {
      const int row = i * 16 + l16;
#pragma unroll
      for (int kc = 0; kc < 2; ++kc)
        vf[i * 2 + kc] = ldv8(Vb + row * 128 + (((kc * 4 + kb) ^ (row & 7)) * 16));
    }

    bf16x4 pwA[4], pwB[4];
    online_sm(sB, pwB, oB, mB, lB, qB, kv0, t == trips - 1);
    if (aAct) online_sm(sA, pwA, oA, mA, lA, qA, kv0, t == pp);

    bf16x8 pbA0, pbA1, pbB0, pbB1;
    p_roundtrip(PB, pwB, pbB0, pbB1);
    if (aAct) p_roundtrip(PA, pwA, pbA0, pbA1);

    __builtin_amdgcn_s_setprio(1);
#pragma unroll
    for (int i = 0; i < 4; ++i) {
      oB[i] = MFMA16(vf[i * 2 + 0], pbB0, oB[i]);
      oB[i] = MFMA16(vf[i * 2 + 1], pbB1, oB[i]);
    }
    if (aAct) {
#pragma unroll
      for (int i = 0; i < 4; ++i) {
        oA[i] = MFMA16(vf[i * 2 + 0], pbA0, oA[i]);
        oA[i] = MFMA16(vf[i * 2 + 1], pbA1, oA[i]);
      }
    }
    __builtin_amdgcn_s_setprio(0);

    asm volatile("s_waitcnt vmcnt(0)" ::: "memory");
    __builtin_amdgcn_s_barrier();
    __builtin_amdgcn_sched_barrier(0);
    cur ^= 1;
  }

  auto epi = [&](const f32x4 (&o)[4], float l_r, int q) {
    const float inv = 1.0f / l_r;
    bf16_t* yrow = Yg + ((size_t)(b * 2048 + q)) * 1024 + h * 64;
#pragma unroll
    for (int i = 0; i < 4; ++i) {
      bf16x4 yv;
      yv[0] = (bf16_t)(o[i][0] * inv);
      yv[1] = (bf16_t)(o[i][1] * inv);
      yv[2] = (bf16_t)(o[i][2] * inv);
      yv[3] = (bf16_t)(o[i][3] * inv);
      *reinterpret_cast<bf16x4*>(yrow + i * 16 + kb * 4) = yv;
    }
  };
  epi(oB, lB, qB);
  epi(oA, lA, qA);
}

// --------------------------------------------------------------- launch ---
extern "C" void kernel_launch(void* const* d_in, const int* in_sizes, int n_in,
                              void* d_out, int out_size, void* d_ws, size_t ws_size,
                              hipStream_t stream) {
  const float* x = (const float*)d_in[0];
  const float* W_attn = (const float*)d_in[1];
  const float* b_attn = (const float*)d_in[2];
  const float* W_proj = (const float*)d_in[3];
  const float* b_proj = (const float*)d_in[4];
  float* out = (float*)d_out;

  char* ws = (char*)d_ws;
  bf16_t* xb  = (bf16_t*)(ws + 0);
  bf16_t* WaT = (bf16_t*)(ws + 16777216);
  bf16_t* WpT = (bf16_t*)(ws + 23068672);
  bf16_t* Qb  = (bf16_t*)(ws + 25165824);
  bf16_t* Kb  = (bf16_t*)(ws + 41943040);
  bf16_t* Vt  = (bf16_t*)(ws + 58720256);
  bf16_t* Yb  = (bf16_t*)(ws + 75497472);

  cvt_f32_bf16<<<8192, 256, 0, stream>>>(x, xb, 8192 * 1024 / 4);
  transpose_cvt<<<dim3(96, 32), dim3(32, 8), 0, stream>>>(W_attn, WaT, 1024, 3072);
  transpose_cvt<<<dim3(32, 32), dim3(32, 8), 0, stream>>>(W_proj, WpT, 1024, 1024);

  gemm_bf16<0><<<dim3(24, 64), 256, 0, stream>>>(xb, WaT, b_attn, 8192, 3072, 1024,
                                                 Qb, Kb, Vt, nullptr);

  attn_fwd<<<1024, 256, 0, stream>>>(Qb, Kb, Vt, Yb);

  gemm_bf16<1><<<dim3(8, 64), 256, 0, stream>>>(Yb, WpT, b_proj, 8192, 1024, 1024,
                                                nullptr, nullptr, nullptr, out);
}